// Round 1
// baseline (100.408 us; speedup 1.0000x reference)
//
#include <hip/hip_runtime.h>
#include <math.h>

#define NN 16384
#define JCHUNK 1024   // j elements staged in LDS per risk-block
#define BLK 256

// ws layout: float2 de[NN] (128 KB) | float risk[NN] (64 KB)

__global__ __launch_bounds__(BLK)
void prep_kernel(const float* __restrict__ hazard,
                 const float* __restrict__ durations,
                 float2* __restrict__ de,
                 float* __restrict__ risk,
                 int n) {
    int i = blockIdx.x * BLK + threadIdx.x;
    if (i < n) {
        de[i] = make_float2(durations[i], expf(hazard[i]));
        risk[i] = 0.0f;
    }
}

__global__ __launch_bounds__(BLK)
void risk_kernel(const float2* __restrict__ de,
                 const float* __restrict__ durations,
                 float* __restrict__ risk,
                 int n) {
    __shared__ float2 tile[JCHUNK];
    const int i  = blockIdx.x * BLK + threadIdx.x;
    const int j0 = blockIdx.y * JCHUNK;

    // stage (duration, exp(theta)) chunk into LDS, coalesced float2 loads
    #pragma unroll
    for (int t = 0; t < JCHUNK / BLK; ++t)
        tile[threadIdx.x + t * BLK] = de[j0 + threadIdx.x + t * BLK];
    __syncthreads();

    const float di = (i < n) ? durations[i] : 0.0f;
    float acc = 0.0f;
    #pragma unroll 8
    for (int jj = 0; jj < JCHUNK; ++jj) {
        float2 v = tile[jj];               // wave-uniform address -> broadcast
        acc += (v.x >= di) ? v.y : 0.0f;   // cmp + cndmask + add
    }
    if (i < n) atomicAdd(&risk[i], acc);   // 16 adds per address total
}

__global__ __launch_bounds__(BLK)
void loss_kernel(const float* __restrict__ hazard,
                 const float* __restrict__ events,
                 const float* __restrict__ risk,
                 float* __restrict__ out,
                 int n) {
    float local = 0.0f;
    for (int i = threadIdx.x; i < n; i += BLK)
        local += (hazard[i] - logf(risk[i])) * events[i];

    // wave-64 butterfly reduce
    #pragma unroll
    for (int o = 32; o > 0; o >>= 1)
        local += __shfl_down(local, o, 64);

    __shared__ float wsum[BLK / 64];
    if ((threadIdx.x & 63) == 0) wsum[threadIdx.x >> 6] = local;
    __syncthreads();
    if (threadIdx.x == 0) {
        float t = 0.0f;
        #pragma unroll
        for (int w = 0; w < BLK / 64; ++w) t += wsum[w];
        out[0] = -t / (float)n;
    }
}

extern "C" void kernel_launch(void* const* d_in, const int* in_sizes, int n_in,
                              void* d_out, int out_size, void* d_ws, size_t ws_size,
                              hipStream_t stream) {
    const float* hazard    = (const float*)d_in[0];   // (N,1) f32
    const float* durations = (const float*)d_in[1];   // (N,)  f32
    const float* events    = (const float*)d_in[2];   // (N,)  f32
    float* out = (float*)d_out;
    const int n = in_sizes[1];

    float2* de   = (float2*)d_ws;
    float*  risk = (float*)((char*)d_ws + (size_t)n * sizeof(float2));

    dim3 pgrid((n + BLK - 1) / BLK);
    prep_kernel<<<pgrid, BLK, 0, stream>>>(hazard, durations, de, risk, n);

    dim3 rgrid((n + BLK - 1) / BLK, (n + JCHUNK - 1) / JCHUNK);
    risk_kernel<<<rgrid, BLK, 0, stream>>>(de, durations, risk, n);

    loss_kernel<<<1, BLK, 0, stream>>>(hazard, events, risk, out, n);
}

// Round 2
// 88.006 us; speedup vs baseline: 1.1409x; 1.1409x over previous
//
#include <hip/hip_runtime.h>
#include <math.h>

#define NN     16384
#define BLK    256
#define IT     8            // i-values per thread
#define IBLK   (BLK * IT)   // 2048 i per block -> 8 i-blocks
#define JCHUNK 256          // j per chunk -> 64 chunks
#define NCHUNK (NN / JCHUNK)

// ws layout:
//   float2 de[NN]                  @ 0        (128 KB)
//   float  partial[NCHUNK][NN]     @ 128 KB   (4 MB)
//   float  wsum                    @ 128 KB + 4 MB

__global__ __launch_bounds__(BLK)
void prep_kernel(const float* __restrict__ hazard,
                 const float* __restrict__ durations,
                 float2* __restrict__ de,
                 float* __restrict__ wsum,
                 int n) {
    int i = blockIdx.x * BLK + threadIdx.x;
    if (i < n)
        de[i] = make_float2(durations[i], expf(hazard[i]));
    if (i == 0) wsum[0] = 0.0f;
}

__global__ __launch_bounds__(BLK)
void risk_kernel(const float2* __restrict__ de,
                 const float* __restrict__ durations,
                 float* __restrict__ partial,
                 int n) {
    __shared__ float2 tile[JCHUNK];
    const int tid   = threadIdx.x;
    const int iBase = blockIdx.x * IBLK;
    const int j0    = blockIdx.y * JCHUNK;

    tile[tid] = de[j0 + tid];           // one coalesced float2 per thread
    __syncthreads();

    float di[IT], acc[IT];
    #pragma unroll
    for (int k = 0; k < IT; ++k) {
        di[k]  = durations[iBase + tid + k * BLK];   // coalesced
        acc[k] = 0.0f;
    }

    #pragma unroll 4
    for (int jj = 0; jj < JCHUNK; ++jj) {
        float2 v = tile[jj];            // 1 ds_read_b64 amortized over 8 pairs
        #pragma unroll
        for (int k = 0; k < IT; ++k)
            acc[k] += (v.x >= di[k]) ? v.y : 0.0f;   // cmp+cndmask+add
    }

    float* out = partial + (size_t)blockIdx.y * n + iBase;
    #pragma unroll
    for (int k = 0; k < IT; ++k)
        out[tid + k * BLK] = acc[k];    // coalesced, no atomics
}

__global__ __launch_bounds__(BLK)
void loss_kernel(const float* __restrict__ hazard,
                 const float* __restrict__ events,
                 const float* __restrict__ partial,
                 float* __restrict__ wsum,
                 int n) {
    const int i = blockIdx.x * BLK + threadIdx.x;   // grid exactly covers n

    float s = 0.0f;
    #pragma unroll 8
    for (int c = 0; c < NCHUNK; ++c)
        s += partial[(size_t)c * n + i];            // coalesced across threads

    float local = (hazard[i] - logf(s)) * events[i];

    #pragma unroll
    for (int o = 32; o > 0; o >>= 1)
        local += __shfl_down(local, o, 64);

    __shared__ float wpart[BLK / 64];
    if ((threadIdx.x & 63) == 0) wpart[threadIdx.x >> 6] = local;
    __syncthreads();
    if (threadIdx.x == 0) {
        float t = 0.0f;
        #pragma unroll
        for (int w = 0; w < BLK / 64; ++w) t += wpart[w];
        atomicAdd(wsum, t);                         // 64 atomics total
    }
}

__global__ void finalize_kernel(const float* __restrict__ wsum,
                                float* __restrict__ out, int n) {
    out[0] = -wsum[0] / (float)n;
}

extern "C" void kernel_launch(void* const* d_in, const int* in_sizes, int n_in,
                              void* d_out, int out_size, void* d_ws, size_t ws_size,
                              hipStream_t stream) {
    const float* hazard    = (const float*)d_in[0];
    const float* durations = (const float*)d_in[1];
    const float* events    = (const float*)d_in[2];
    float* out = (float*)d_out;
    const int n = in_sizes[1];

    float2* de      = (float2*)d_ws;
    float*  partial = (float*)((char*)d_ws + (size_t)n * sizeof(float2));
    float*  wsum    = partial + (size_t)NCHUNK * n;

    prep_kernel<<<dim3((n + BLK - 1) / BLK), BLK, 0, stream>>>(hazard, durations, de, wsum, n);

    dim3 rgrid(n / IBLK, NCHUNK);   // 8 x 64 = 512 blocks, 2/CU
    risk_kernel<<<rgrid, BLK, 0, stream>>>(de, durations, partial, n);

    loss_kernel<<<dim3(n / BLK), BLK, 0, stream>>>(hazard, events, partial, wsum, n);

    finalize_kernel<<<1, 1, 0, stream>>>(wsum, out, n);
}

// Round 3
// 76.000 us; speedup vs baseline: 1.3211x; 1.1580x over previous
//
#include <hip/hip_runtime.h>
#include <math.h>

#define NB    2048
#define BLK   256
#define SCANT 1024

// ws layout (bytes):
//   0      : float  sumExp[NB]    (8192)   -- zeroed each call
//   8192   : int    cnt[NB]       (8192)   -- zeroed each call
//   16384  : float  wsum                   -- zeroed each call
//   16388  : int    done                   -- zeroed each call
//   16640  : int    offsets[NB]   (8192)
//   24832  : int    cursor[NB]    (8192)
//   33024  : float  suffixGT[NB]  (8192)
//   41216  : float2 sorted[N]     (131072)

__device__ __forceinline__ int bucket_of(float d) {
    int b = (int)(d * (float)NB);          // monotone non-decreasing in d
    return min(max(b, 0), NB - 1);
}

__global__ __launch_bounds__(BLK)
void zero_kernel(int* __restrict__ ws_i) {  // zero first 16392 bytes
    int i = blockIdx.x * BLK + threadIdx.x;
    if (i < 4098) ws_i[i] = 0;
}

__global__ __launch_bounds__(BLK)
void stats_kernel(const float* __restrict__ hazard,
                  const float* __restrict__ durations,
                  float* __restrict__ sumExp, int* __restrict__ cnt, int n) {
    int j = blockIdx.x * BLK + threadIdx.x;
    if (j >= n) return;
    float d = durations[j];
    float e = expf(hazard[j]);
    int b = bucket_of(d);
    atomicAdd(&sumExp[b], e);   // avg 8 collisions/bucket
    atomicAdd(&cnt[b], 1);
}

__global__ __launch_bounds__(SCANT)
void scan_kernel(const float* __restrict__ sumExp, const int* __restrict__ cnt,
                 int* __restrict__ offsets, int* __restrict__ cursor,
                 float* __restrict__ suffixGT) {
    __shared__ float fa[NB], fb[NB];
    __shared__ int   ia[NB], ib[NB];
    const int tid = threadIdx.x;

    #pragma unroll
    for (int k = 0; k < NB / SCANT; ++k) {
        int idx = tid + k * SCANT;
        fa[idx] = sumExp[NB - 1 - idx];   // reversed -> suffix via prefix
        ia[idx] = cnt[idx];
    }
    __syncthreads();

    bool pa = true;
    for (int d = 1; d < NB; d <<= 1) {    // Hillis-Steele inclusive scan
        #pragma unroll
        for (int k = 0; k < NB / SCANT; ++k) {
            int idx = tid + k * SCANT;
            float fsrc = pa ? fa[idx] : fb[idx];
            int   isrc = pa ? ia[idx] : ib[idx];
            float fadd = (idx >= d) ? (pa ? fa[idx - d] : fb[idx - d]) : 0.0f;
            int   iadd = (idx >= d) ? (pa ? ia[idx - d] : ib[idx - d]) : 0;
            if (pa) { fb[idx] = fsrc + fadd; ib[idx] = isrc + iadd; }
            else    { fa[idx] = fsrc + fadd; ia[idx] = isrc + iadd; }
        }
        __syncthreads();
        pa = !pa;
    }
    // results in (pa ? fa/ia : fb/ib)
    #pragma unroll
    for (int k = 0; k < NB / SCANT; ++k) {
        int idx = tid + k * SCANT;
        int iexcl = (idx > 0) ? (pa ? ia[idx - 1] : ib[idx - 1]) : 0;
        offsets[idx] = iexcl;
        cursor[idx]  = iexcl;
        // suffixGT[b] = sum_{b'>b} sumExp[b'] = revScan[NB-2-b]
        suffixGT[idx] = (idx + 1 < NB) ? (pa ? fa[NB - 2 - idx] : fb[NB - 2 - idx]) : 0.0f;
    }
}

__global__ __launch_bounds__(BLK)
void scatter_kernel(const float* __restrict__ hazard,
                    const float* __restrict__ durations,
                    const int* __restrict__ offsets,  // unused directly; cursor pre-set
                    int* __restrict__ cursor,
                    float2* __restrict__ sorted, int n) {
    int j = blockIdx.x * BLK + threadIdx.x;
    if (j >= n) return;
    float d = durations[j];
    float e = expf(hazard[j]);
    int b = bucket_of(d);
    int pos = atomicAdd(&cursor[b], 1);
    sorted[pos] = make_float2(d, e);
}

__global__ __launch_bounds__(BLK)
void loss_kernel(const float* __restrict__ hazard,
                 const float* __restrict__ durations,
                 const float* __restrict__ events,
                 const int* __restrict__ offsets, const int* __restrict__ cnt,
                 const float* __restrict__ suffixGT,
                 const float2* __restrict__ sorted,
                 float* __restrict__ wsum, int* __restrict__ done,
                 float* __restrict__ out, int n) {
    const int i = blockIdx.x * BLK + threadIdx.x;   // grid covers n exactly
    float d = durations[i];
    int b = bucket_of(d);
    float s = suffixGT[b];
    int off = offsets[b], c = cnt[b];
    for (int k = 0; k < c; ++k) {                   // avg 8, max ~35
        float2 v = sorted[off + k];
        s += (v.x >= d) ? v.y : 0.0f;               // includes j==i -> s > 0
    }
    float local = (hazard[i] - logf(s)) * events[i];

    #pragma unroll
    for (int o = 32; o > 0; o >>= 1)
        local += __shfl_down(local, o, 64);

    __shared__ float wpart[BLK / 64];
    if ((threadIdx.x & 63) == 0) wpart[threadIdx.x >> 6] = local;
    __syncthreads();
    if (threadIdx.x == 0) {
        float t = 0.0f;
        #pragma unroll
        for (int w = 0; w < BLK / 64; ++w) t += wpart[w];
        atomicAdd(wsum, t);
        __threadfence();
        int ticket = atomicAdd(done, 1);
        if (ticket == (int)gridDim.x - 1) {         // last block finalizes
            float tot = atomicAdd(wsum, 0.0f);      // atomic read: all adds visible
            out[0] = -tot / (float)n;
        }
    }
}

extern "C" void kernel_launch(void* const* d_in, const int* in_sizes, int n_in,
                              void* d_out, int out_size, void* d_ws, size_t ws_size,
                              hipStream_t stream) {
    const float* hazard    = (const float*)d_in[0];
    const float* durations = (const float*)d_in[1];
    const float* events    = (const float*)d_in[2];
    float* out = (float*)d_out;
    const int n = in_sizes[1];

    char* ws = (char*)d_ws;
    float*  sumExp   = (float*)(ws + 0);
    int*    cnt      = (int*)  (ws + 8192);
    float*  wsum     = (float*)(ws + 16384);
    int*    done     = (int*)  (ws + 16388);
    int*    offsets  = (int*)  (ws + 16640);
    int*    cursor   = (int*)  (ws + 24832);
    float*  suffixGT = (float*)(ws + 33024);
    float2* sorted   = (float2*)(ws + 41216);

    const int nblk = (n + BLK - 1) / BLK;   // 64

    zero_kernel   <<<17, BLK, 0, stream>>>((int*)ws);
    stats_kernel  <<<nblk, BLK, 0, stream>>>(hazard, durations, sumExp, cnt, n);
    scan_kernel   <<<1, SCANT, 0, stream>>>(sumExp, cnt, offsets, cursor, suffixGT);
    scatter_kernel<<<nblk, BLK, 0, stream>>>(hazard, durations, offsets, cursor, sorted, n);
    loss_kernel   <<<nblk, BLK, 0, stream>>>(hazard, durations, events, offsets, cnt,
                                             suffixGT, sorted, wsum, done, out, n);
}